// Round 4
// baseline (39978.870 us; speedup 1.0000x reference)
//
#include <hip/hip_runtime.h>
#include <hip/hip_bf16.h>
#include <hip/hip_fp16.h>

#define T_LEN 32768
#define NDIM 256
#define NFFN 1024

typedef __attribute__((ext_vector_type(8))) short bf8v;      // 8 bf16 (4 VGPRs)
typedef __attribute__((ext_vector_type(8))) _Float16 h8v;    // 8 f16 (4 VGPRs)
typedef __attribute__((ext_vector_type(4))) float f4v;       // MFMA accum
typedef _Float16 fp16_t;

__device__ __forceinline__ unsigned short f2bf(float f) {
  union { float f; unsigned int i; } v; v.f = f;
  unsigned int u = v.i;
  u += 0x7FFFu + ((u >> 16) & 1u);   // RNE
  return (unsigned short)(u >> 16);
}

// A/B fragment loaders for mfma_f32_16x16x32_bf16.
__device__ __forceinline__ bf8v load_frag(const unsigned short* base, int ld, int r0, int k0) {
  int lane = threadIdx.x & 63;
  const unsigned short* p = base + (size_t)(r0 + (lane & 15)) * ld + (k0 + ((lane >> 4) << 3));
  return *(const bf8v*)p;
}
__device__ __forceinline__ bf8v load_frag_f32(const float* base, int ld, int r0, int k0) {
  int lane = threadIdx.x & 63;
  const float* p = base + (size_t)(r0 + (lane & 15)) * ld + (k0 + ((lane >> 4) << 3));
  float4 u = *(const float4*)p;
  float4 v = *(const float4*)(p + 4);
  bf8v r;
  r[0] = (short)f2bf(u.x); r[1] = (short)f2bf(u.y); r[2] = (short)f2bf(u.z); r[3] = (short)f2bf(u.w);
  r[4] = (short)f2bf(v.x); r[5] = (short)f2bf(v.y); r[6] = (short)f2bf(v.z); r[7] = (short)f2bf(v.w);
  return r;
}

// ---------------- K0a: transpose f32 [K,N] -> bf16 [N,K] ----------------
__global__ __launch_bounds__(256) void k_tr_bf(const float* __restrict__ src,
                                               unsigned short* __restrict__ dst, int K, int N) {
  int idx = blockIdx.x * 256 + threadIdx.x;
  if (idx >= K * N) return;
  int k = idx / N, n = idx - k * N;
  dst[n * K + k] = f2bf(src[idx]);
}
// ---------------- K0b: transpose f32 [K,N] -> f16 [N,K] (for GRU Wh) ----------------
__global__ __launch_bounds__(256) void k_tr_h(const float* __restrict__ src,
                                              fp16_t* __restrict__ dst, int K, int N) {
  int idx = blockIdx.x * 256 + threadIdx.x;
  if (idx >= K * N) return;
  int k = idx / N, n = idx - k * N;
  dst[n * K + k] = (fp16_t)src[idx];
}

// ---------------- K1: xg = xs @ Wi  ([T,256]f32 @ [256,768] -> f16 [T,768]) ----------------
__global__ __launch_bounds__(256) void k_xg(const float* __restrict__ xs,
                                            const unsigned short* __restrict__ WiT,
                                            __half* __restrict__ xg) {
  int mt = blockIdx.x, ns = blockIdx.y;
  int wave = threadIdx.x >> 6, lane = threadIdx.x & 63;
  int r0 = mt * 16;
  f4v acc[4];
#pragma unroll
  for (int i = 0; i < 4; ++i) acc[i] = (f4v){0.f, 0.f, 0.f, 0.f};
#pragma unroll
  for (int kc = 0; kc < 256; kc += 32) {
    bf8v a = load_frag_f32(xs, NDIM, r0, kc);
#pragma unroll
    for (int nt = 0; nt < 4; ++nt) {
      int c0 = ns * 256 + wave * 64 + nt * 16;
      bf8v b = load_frag(WiT, NDIM, c0, kc);
      acc[nt] = __builtin_amdgcn_mfma_f32_16x16x32_bf16(a, b, acc[nt], 0, 0, 0);
    }
  }
#pragma unroll
  for (int nt = 0; nt < 4; ++nt) {
    int col = ns * 256 + wave * 64 + nt * 16 + (lane & 15);
    int rb = r0 + ((lane >> 4) << 2);
#pragma unroll
    for (int r = 0; r < 4; ++r)
      xg[(size_t)(rb + r) * 768 + col] = (__half)acc[nt][r];
  }
}

// ---------------- K2: sequential GRU scan — MFMA recurrence ----------------
// 512 threads (8 waves, 2/SIMD). D = A*B with A = h broadcast to all 16 rows
// (lane's A-frag depends only on copy=lane>>4 -> LDS broadcast read), B = Wh
// fragments resident in AGPRs (48 tiles x 4 regs; MFMA reads AGPRs natively,
// no accvgpr shuttling). Wave w covers cols jA=32w+c, jB=jA+16 for gates
// r/z/n -> gate math fully in-register; one barrier/step via hbuf double-buffer.
__global__ __launch_bounds__(512, 2) void k_gru(const fp16_t* __restrict__ WhT,
                                                const float* __restrict__ bh,
                                                const float* __restrict__ h0,
                                                const __half* __restrict__ xg,
                                                unsigned short* __restrict__ relu_ys) {
  __shared__ __align__(16) fp16_t hbuf[2][256];
  const int tid = threadIdx.x;
  const int w = tid >> 6, lane = tid & 63;
  const int c = lane & 15, copy = lane >> 4;
  const int jA = 32 * w + c, jB = jA + 16;

  // B-fragments: tiles 0..5 = {r/jA, r/jB, z/jA, z/jB, n/jA, n/jB}
  // tile col-bases:
  int cbs[6] = { 32 * w, 32 * w + 16, 256 + 32 * w, 256 + 32 * w + 16,
                 512 + 32 * w, 512 + 32 * w + 16 };
  h8v Bf[6][8];
#pragma unroll
  for (int ti = 0; ti < 6; ++ti) {
    const fp16_t* p = WhT + (size_t)(cbs[ti] + c) * 256 + copy * 8;
#pragma unroll
    for (int kc = 0; kc < 8; ++kc)
      Bf[ti][kc] = *(const h8v*)(p + kc * 32);
  }

  // per-lane biases and initial state
  float bhrA = bh[jA], bhrB = bh[jB];
  float bhzA = bh[256 + jA], bhzB = bh[256 + jB];
  float bhnA = bh[512 + jA], bhnB = bh[512 + jB];
  float hA = h0[jA], hB = h0[jB];
  if (copy == 0) {
    hbuf[0][jA] = (fp16_t)hA;
    hbuf[0][jB] = (fp16_t)hB;
  }
  // xg values for t=0
  float xrA = (float)xg[jA],       xrB = (float)xg[jB];
  float xzA = (float)xg[256 + jA], xzB = (float)xg[256 + jB];
  float xnA = (float)xg[512 + jA], xnB = (float)xg[512 + jB];
  __syncthreads();

  for (int t = 0; t < T_LEN; ++t) {
    const int p = t & 1;
    f4v acc[6];
#pragma unroll
    for (int i = 0; i < 6; ++i) acc[i] = (f4v){0.f, 0.f, 0.f, 0.f};
#pragma unroll
    for (int kc = 0; kc < 8; ++kc) {
      h8v a = *(const h8v*)(&hbuf[p][kc * 32 + copy * 8]);   // broadcast across c
#pragma unroll
      for (int ti = 0; ti < 6; ++ti)
        acc[ti] = __builtin_amdgcn_mfma_f32_16x16x32_f16(a, Bf[ti][kc], acc[ti], 0, 0, 0);
    }
    // all 4 D-rows equal -> take reg 0
    float hrA = acc[0][0] + bhrA, hrB = acc[1][0] + bhrB;
    float hzA = acc[2][0] + bhzA, hzB = acc[3][0] + bhzB;
    float hnA = acc[4][0] + bhnA, hnB = acc[5][0] + bhnB;

    float rA = 1.f / (1.f + __expf(-(xrA + hrA)));
    float rB = 1.f / (1.f + __expf(-(xrB + hrB)));
    float zA = 1.f / (1.f + __expf(-(xzA + hzA)));
    float zB = 1.f / (1.f + __expf(-(xzB + hzB)));
    float aA = xnA + rA * hnA, aB = xnB + rB * hnB;
    float eA = __expf(-2.f * fabsf(aA)), eB = __expf(-2.f * fabsf(aB));
    float nA = copysignf((1.f - eA) / (1.f + eA), aA);
    float nB = copysignf((1.f - eB) / (1.f + eB), aB);
    hA = (1.f - zA) * nA + zA * hA;
    hB = (1.f - zB) * nB + zB * hB;

    if (copy == 0) {
      hbuf[p ^ 1][jA] = (fp16_t)hA;
      hbuf[p ^ 1][jB] = (fp16_t)hB;
      relu_ys[(size_t)t * NDIM + jA] = f2bf(fmaxf(hA, 0.f));
      relu_ys[(size_t)t * NDIM + jB] = f2bf(fmaxf(hB, 0.f));
    }
    // prefetch next step's xg (wraps at end; values unused then)
    const __half* row = xg + (size_t)((t + 1) & (T_LEN - 1)) * 768;
    xrA = (float)row[jA];       xrB = (float)row[jB];
    xzA = (float)row[256 + jA]; xzB = (float)row[256 + jB];
    xnA = (float)row[512 + jA]; xnB = (float)row[512 + jB];
    __syncthreads();
  }
}

// ---------------- K3: y = LN(xs + relu(ys)@Wg + bg) * g1 + be1  (y: f32) ----------------
__global__ __launch_bounds__(256) void k_res_ln1(const unsigned short* __restrict__ rys,
                                                 const unsigned short* __restrict__ WgT,
                                                 const float* __restrict__ xs,
                                                 const float* __restrict__ bg,
                                                 const float* __restrict__ g1,
                                                 const float* __restrict__ be1,
                                                 float* __restrict__ y) {
  __shared__ float sbuf[16][264];
  int mt = blockIdx.x, tid = threadIdx.x;
  int wave = tid >> 6, lane = tid & 63;
  int r0 = mt * 16;
  f4v acc[4];
#pragma unroll
  for (int i = 0; i < 4; ++i) acc[i] = (f4v){0.f, 0.f, 0.f, 0.f};
#pragma unroll
  for (int kc = 0; kc < 256; kc += 32) {
    bf8v a = load_frag(rys, NDIM, r0, kc);
#pragma unroll
    for (int nt = 0; nt < 4; ++nt) {
      bf8v b = load_frag(WgT, NDIM, wave * 64 + nt * 16, kc);
      acc[nt] = __builtin_amdgcn_mfma_f32_16x16x32_bf16(a, b, acc[nt], 0, 0, 0);
    }
  }
#pragma unroll
  for (int nt = 0; nt < 4; ++nt) {
    int col = wave * 64 + nt * 16 + (lane & 15);
    int rl = ((lane >> 4) << 2);
#pragma unroll
    for (int r = 0; r < 4; ++r)
      sbuf[rl + r][col] = acc[nt][r] + xs[(size_t)(r0 + rl + r) * NDIM + col] + bg[col];
  }
  __syncthreads();
  int rr = tid >> 4, c0 = tid & 15;
  float sum = 0.f, sq = 0.f;
#pragma unroll
  for (int m = 0; m < 16; ++m) {
    float v = sbuf[rr][c0 + 16 * m];
    sum += v; sq += v * v;
  }
#pragma unroll
  for (int o = 1; o < 16; o <<= 1) {
    sum += __shfl_xor(sum, o, 16);
    sq  += __shfl_xor(sq, o, 16);
  }
  float mu = sum * (1.f / 256.f);
  float var = sq * (1.f / 256.f) - mu * mu;
  float rs = rsqrtf(var + 1e-6f);
#pragma unroll
  for (int m = 0; m < 16; ++m) {
    int col = c0 + 16 * m;
    float v = (sbuf[rr][col] - mu) * rs * g1[col] + be1[col];
    y[(size_t)(r0 + rr) * NDIM + col] = v;
  }
}

// ---------------- K4: out = LN(y + relu(y@W1+b1)@W2 + b2) * g2 + be2 ----------------
__global__ __launch_bounds__(256) void k_ffn(const float* __restrict__ y,
                                             const unsigned short* __restrict__ W1T,
                                             const float* __restrict__ b1,
                                             const unsigned short* __restrict__ W2T,
                                             const float* __restrict__ b2,
                                             const float* __restrict__ g2,
                                             const float* __restrict__ be2,
                                             float* __restrict__ out) {
  __shared__ unsigned short hidb[16][1032];
  __shared__ float sbuf[16][264];
  int mt = blockIdx.x, tid = threadIdx.x;
  int wave = tid >> 6, lane = tid & 63;
  int r0 = mt * 16;

  f4v acc1[16];
#pragma unroll
  for (int i = 0; i < 16; ++i) acc1[i] = (f4v){0.f, 0.f, 0.f, 0.f};
#pragma unroll
  for (int kc = 0; kc < 256; kc += 32) {
    bf8v a = load_frag_f32(y, NDIM, r0, kc);
#pragma unroll
    for (int nt = 0; nt < 16; ++nt) {
      bf8v b = load_frag(W1T, NDIM, wave * 256 + nt * 16, kc);
      acc1[nt] = __builtin_amdgcn_mfma_f32_16x16x32_bf16(a, b, acc1[nt], 0, 0, 0);
    }
  }
#pragma unroll
  for (int nt = 0; nt < 16; ++nt) {
    int col = wave * 256 + nt * 16 + (lane & 15);
    int rl = ((lane >> 4) << 2);
#pragma unroll
    for (int r = 0; r < 4; ++r)
      hidb[rl + r][col] = f2bf(fmaxf(acc1[nt][r] + b1[col], 0.f));
  }
  __syncthreads();

  f4v acc2[4];
#pragma unroll
  for (int i = 0; i < 4; ++i) acc2[i] = (f4v){0.f, 0.f, 0.f, 0.f};
  for (int kc = 0; kc < 1024; kc += 32) {
    bf8v a = *(const bf8v*)(&hidb[lane & 15][kc + ((lane >> 4) << 3)]);
#pragma unroll
    for (int nt = 0; nt < 4; ++nt) {
      bf8v b = load_frag(W2T, NFFN, wave * 64 + nt * 16, kc);
      acc2[nt] = __builtin_amdgcn_mfma_f32_16x16x32_bf16(a, b, acc2[nt], 0, 0, 0);
    }
  }
#pragma unroll
  for (int nt = 0; nt < 4; ++nt) {
    int col = wave * 64 + nt * 16 + (lane & 15);
    int rl = ((lane >> 4) << 2);
#pragma unroll
    for (int r = 0; r < 4; ++r)
      sbuf[rl + r][col] = acc2[nt][r] + y[(size_t)(r0 + rl + r) * NDIM + col] + b2[col];
  }
  __syncthreads();
  int rr = tid >> 4, c0 = tid & 15;
  float sum = 0.f, sq = 0.f;
#pragma unroll
  for (int m = 0; m < 16; ++m) {
    float v = sbuf[rr][c0 + 16 * m];
    sum += v; sq += v * v;
  }
#pragma unroll
  for (int o = 1; o < 16; o <<= 1) {
    sum += __shfl_xor(sum, o, 16);
    sq  += __shfl_xor(sq, o, 16);
  }
  float mu = sum * (1.f / 256.f);
  float var = sq * (1.f / 256.f) - mu * mu;
  float rs = rsqrtf(var + 1e-6f);
#pragma unroll
  for (int m = 0; m < 16; ++m) {
    int col = c0 + 16 * m;
    float v = (sbuf[rr][col] - mu) * rs * g2[col] + be2[col];
    out[(size_t)(r0 + rr) * NDIM + col] = v;
  }
}

// ---------------- host ----------------
extern "C" void kernel_launch(void* const* d_in, const int* in_sizes, int n_in,
                              void* d_out, int out_size, void* d_ws, size_t ws_size,
                              hipStream_t stream) {
  const float* xs  = (const float*)d_in[0];
  const float* h0  = (const float*)d_in[1];
  const float* Wi  = (const float*)d_in[2];
  const float* Wh  = (const float*)d_in[3];
  const float* bh  = (const float*)d_in[4];
  const float* Wg  = (const float*)d_in[5];
  const float* bg  = (const float*)d_in[6];
  const float* g1  = (const float*)d_in[7];
  const float* be1 = (const float*)d_in[8];
  const float* W1  = (const float*)d_in[9];
  const float* b1  = (const float*)d_in[10];
  const float* W2  = (const float*)d_in[11];
  const float* b2  = (const float*)d_in[12];
  const float* g2  = (const float*)d_in[13];
  const float* be2 = (const float*)d_in[14];

  char* ws = (char*)d_ws;
  __half* xg = (__half*)(ws + 0);          // f16 [T,768] = 50331648 B
  float*  yb = (float*)(ws + 0);           // reuses xg region AFTER k_gru
  unsigned short* rys = (unsigned short*)(ws + 50331648);   // bf16 [T,256]
  unsigned short* WiT = (unsigned short*)(ws + 67108864);
  fp16_t*         WhT = (fp16_t*)        (ws + 67502080);
  unsigned short* WgT = (unsigned short*)(ws + 67895296);
  unsigned short* W1T = (unsigned short*)(ws + 68026368);
  unsigned short* W2T = (unsigned short*)(ws + 68550656);

  k_tr_bf<<<(256 * 768 + 255) / 256, 256, 0, stream>>>(Wi, WiT, 256, 768);
  k_tr_h <<<(256 * 768 + 255) / 256, 256, 0, stream>>>(Wh, WhT, 256, 768);
  k_tr_bf<<<(256 * 256 + 255) / 256, 256, 0, stream>>>(Wg, WgT, 256, 256);
  k_tr_bf<<<(256 * 1024 + 255) / 256, 256, 0, stream>>>(W1, W1T, 256, 1024);
  k_tr_bf<<<(1024 * 256 + 255) / 256, 256, 0, stream>>>(W2, W2T, 1024, 256);

  k_xg<<<dim3(T_LEN / 16, 3), 256, 0, stream>>>(xs, WiT, xg);
  k_gru<<<1, 512, 0, stream>>>(WhT, bh, h0, xg, rys);
  k_res_ln1<<<T_LEN / 16, 256, 0, stream>>>(rys, WgT, xs, bg, g1, be1, yb);
  k_ffn<<<T_LEN / 16, 256, 0, stream>>>(yb, W1T, b1, W2T, b2, g2, be2, (float*)d_out);
}

// Round 6
// 30519.775 us; speedup vs baseline: 1.3099x; 1.3099x over previous
//
#include <hip/hip_runtime.h>
#include <hip/hip_bf16.h>
#include <hip/hip_fp16.h>

#define T_LEN 32768
#define NDIM 256
#define NFFN 1024

typedef __attribute__((ext_vector_type(8))) short bf8v;      // 8 bf16 (4 VGPRs)
typedef __attribute__((ext_vector_type(4))) float f4v;       // f32 MFMA accum
typedef __attribute__((ext_vector_type(4))) int   i4v;       // 4 dwords (16 int8) / i32 accum
typedef _Float16 fp16_t;

__device__ __forceinline__ unsigned short f2bf(float f) {
  union { float f; unsigned int i; } v; v.f = f;
  unsigned int u = v.i;
  u += 0x7FFFu + ((u >> 16) & 1u);   // RNE
  return (unsigned short)(u >> 16);
}

// A/B fragment loaders for mfma_f32_16x16x32_bf16.
__device__ __forceinline__ bf8v load_frag(const unsigned short* base, int ld, int r0, int k0) {
  int lane = threadIdx.x & 63;
  const unsigned short* p = base + (size_t)(r0 + (lane & 15)) * ld + (k0 + ((lane >> 4) << 3));
  return *(const bf8v*)p;
}
__device__ __forceinline__ bf8v load_frag_f32(const float* base, int ld, int r0, int k0) {
  int lane = threadIdx.x & 63;
  const float* p = base + (size_t)(r0 + (lane & 15)) * ld + (k0 + ((lane >> 4) << 3));
  float4 u = *(const float4*)p;
  float4 v = *(const float4*)(p + 4);
  bf8v r;
  r[0] = (short)f2bf(u.x); r[1] = (short)f2bf(u.y); r[2] = (short)f2bf(u.z); r[3] = (short)f2bf(u.w);
  r[4] = (short)f2bf(v.x); r[5] = (short)f2bf(v.y); r[6] = (short)f2bf(v.z); r[7] = (short)f2bf(v.w);
  return r;
}

// ---------------- K0a: transpose f32 [K,N] -> bf16 [N,K] ----------------
__global__ __launch_bounds__(256) void k_tr_bf(const float* __restrict__ src,
                                               unsigned short* __restrict__ dst, int K, int N) {
  int idx = blockIdx.x * 256 + threadIdx.x;
  if (idx >= K * N) return;
  int k = idx / N, n = idx - k * N;
  dst[n * K + k] = f2bf(src[idx]);
}

// ---------------- K0b: quantize Wh f32 [256][768] -> int8 [768][256] + per-col dequant F ---------
// block j (768 blocks, 64 threads): colmax reduce -> scale -> quantize col j.
__global__ __launch_bounds__(64) void k_prep(const float* __restrict__ Wh,
                                             char* __restrict__ WhQ,
                                             float* __restrict__ F) {
  int j = blockIdx.x, t = threadIdx.x;
  float w[4]; float m = 0.f;
#pragma unroll
  for (int i = 0; i < 4; ++i) {
    w[i] = Wh[(size_t)(t + 64 * i) * 768 + j];
    m = fmaxf(m, fabsf(w[i]));
  }
#pragma unroll
  for (int off = 32; off >= 1; off >>= 1) m = fmaxf(m, __shfl_xor(m, off));
  float mm = fmaxf(m, 1e-20f);
  float inv = 127.f / mm;
#pragma unroll
  for (int i = 0; i < 4; ++i) {
    int qv = (int)rintf(w[i] * inv);
    WhQ[(size_t)j * 256 + t + 64 * i] = (char)qv;
  }
  if (t == 0) F[j] = mm * (1.f / (127.f * 127.f));   // hg = acc_i32 * F
}

// ---------------- K1: xg = xs @ Wi  ([T,256]f32 @ [256,768] -> f16 [T,768]) ----------------
__global__ __launch_bounds__(256) void k_xg(const float* __restrict__ xs,
                                            const unsigned short* __restrict__ WiT,
                                            __half* __restrict__ xg) {
  int mt = blockIdx.x, ns = blockIdx.y;
  int wave = threadIdx.x >> 6, lane = threadIdx.x & 63;
  int r0 = mt * 16;
  f4v acc[4];
#pragma unroll
  for (int i = 0; i < 4; ++i) acc[i] = (f4v){0.f, 0.f, 0.f, 0.f};
#pragma unroll
  for (int kc = 0; kc < 256; kc += 32) {
    bf8v a = load_frag_f32(xs, NDIM, r0, kc);
#pragma unroll
    for (int nt = 0; nt < 4; ++nt) {
      int c0 = ns * 256 + wave * 64 + nt * 16;
      bf8v b = load_frag(WiT, NDIM, c0, kc);
      acc[nt] = __builtin_amdgcn_mfma_f32_16x16x32_bf16(a, b, acc[nt], 0, 0, 0);
    }
  }
#pragma unroll
  for (int nt = 0; nt < 4; ++nt) {
    int col = ns * 256 + wave * 64 + nt * 16 + (lane & 15);
    int rb = r0 + ((lane >> 4) << 2);
#pragma unroll
    for (int r = 0; r < 4; ++r)
      xg[(size_t)(rb + r) * 768 + col] = (__half)acc[nt][r];
  }
}

// ---------------- K2: sequential GRU scan — int8 MFMA recurrence ----------------
// 512 threads (8 waves, 2/SIMD). D = A*B, A = int8 h broadcast to all 16 rows
// (lane A-frag depends only on copy=lane>>4 -> LDS broadcast), B = int8 Wh
// fragments resident in AGPRs (24 frags x 4 regs; MFMA reads AGPRs natively).
// K=64 per MFMA -> 192 MFMAs/step (half of the f16 version). i32 accumulation
// is exact; per-column dequant scale F. Wave w covers cols jA=32w+c, jB=jA+16
// for gates r/z/n; one barrier/step via int8 hbuf double-buffer.
__global__ __launch_bounds__(512, 2) void k_gru(const char* __restrict__ WhQ,
                                                const float* __restrict__ F,
                                                const float* __restrict__ bh,
                                                const float* __restrict__ h0,
                                                const __half* __restrict__ xg,
                                                unsigned short* __restrict__ relu_ys) {
  __shared__ __align__(16) char hbuf[2][256];
  const int tid = threadIdx.x;
  const int w = tid >> 6, lane = tid & 63;
  const int c = lane & 15, copy = lane >> 4;
  const int jA = 32 * w + c, jB = jA + 16;

  // B-fragments: tiles 0..5 = {r/jA-tile, r/jB-tile, z/jA, z/jB, n/jA, n/jB}
  int cbs[6] = { 32 * w, 32 * w + 16, 256 + 32 * w, 256 + 32 * w + 16,
                 512 + 32 * w, 512 + 32 * w + 16 };
  i4v BQ[6][4];
#pragma unroll
  for (int ti = 0; ti < 6; ++ti) {
    const i4v* p = (const i4v*)(WhQ + (size_t)(cbs[ti] + c) * 256 + copy * 16);
#pragma unroll
    for (int kt = 0; kt < 4; ++kt)
      BQ[ti][kt] = p[kt * 4];              // +kt*64 bytes
  }

  // per-lane dequant scales and biases
  float FrA = F[jA],       FrB = F[jB];
  float FzA = F[256 + jA], FzB = F[256 + jB];
  float FnA = F[512 + jA], FnB = F[512 + jB];
  float bhrA = bh[jA],       bhrB = bh[jB];
  float bhzA = bh[256 + jA], bhzB = bh[256 + jB];
  float bhnA = bh[512 + jA], bhnB = bh[512 + jB];
  float hA = h0[jA], hB = h0[jB];
  if (copy == 0) {
    int qA = max(-127, min(127, (int)rintf(hA * 127.f)));
    int qB = max(-127, min(127, (int)rintf(hB * 127.f)));
    hbuf[0][jA] = (char)qA;
    hbuf[0][jB] = (char)qB;
  }
  float xrA = (float)xg[jA],       xrB = (float)xg[jB];
  float xzA = (float)xg[256 + jA], xzB = (float)xg[256 + jB];
  float xnA = (float)xg[512 + jA], xnB = (float)xg[512 + jB];
  __syncthreads();

  for (int t = 0; t < T_LEN; ++t) {
    const int p = t & 1;
    i4v acc[6];
#pragma unroll
    for (int i = 0; i < 6; ++i) acc[i] = (i4v){0, 0, 0, 0};
#pragma unroll
    for (int kt = 0; kt < 4; ++kt) {
      i4v a = *(const i4v*)(&hbuf[p][kt * 64 + copy * 16]);   // broadcast across c
#pragma unroll
      for (int ti = 0; ti < 6; ++ti)
        acc[ti] = __builtin_amdgcn_mfma_i32_16x16x64_i8(a, BQ[ti][kt], acc[ti], 0, 0, 0);
    }
    // all D-rows equal (A rows identical) -> take reg 0
    float hrA = (float)acc[0][0] * FrA + bhrA;
    float hrB = (float)acc[1][0] * FrB + bhrB;
    float hzA = (float)acc[2][0] * FzA + bhzA;
    float hzB = (float)acc[3][0] * FzB + bhzB;
    float hnA = (float)acc[4][0] * FnA + bhnA;
    float hnB = (float)acc[5][0] * FnB + bhnB;

    float rA = 1.f / (1.f + __expf(-(xrA + hrA)));
    float rB = 1.f / (1.f + __expf(-(xrB + hrB)));
    float zA = 1.f / (1.f + __expf(-(xzA + hzA)));
    float zB = 1.f / (1.f + __expf(-(xzB + hzB)));
    float aA = xnA + rA * hnA, aB = xnB + rB * hnB;
    float eA = __expf(-2.f * fabsf(aA)), eB = __expf(-2.f * fabsf(aB));
    float nA = copysignf((1.f - eA) / (1.f + eA), aA);   // tanh, NaN-safe
    float nB = copysignf((1.f - eB) / (1.f + eB), aB);
    hA = (1.f - zA) * nA + zA * hA;
    hB = (1.f - zB) * nB + zB * hB;

    if (copy == 0) {
      int qA = max(-127, min(127, (int)rintf(hA * 127.f)));
      int qB = max(-127, min(127, (int)rintf(hB * 127.f)));
      hbuf[p ^ 1][jA] = (char)qA;
      hbuf[p ^ 1][jB] = (char)qB;
      relu_ys[(size_t)t * NDIM + jA] = f2bf(fmaxf(hA, 0.f));
      relu_ys[(size_t)t * NDIM + jB] = f2bf(fmaxf(hB, 0.f));
    }
    // prefetch next step's xg (wraps at end; values unused then)
    const __half* row = xg + (size_t)((t + 1) & (T_LEN - 1)) * 768;
    xrA = (float)row[jA];       xrB = (float)row[jB];
    xzA = (float)row[256 + jA]; xzB = (float)row[256 + jB];
    xnA = (float)row[512 + jA]; xnB = (float)row[512 + jB];
    __syncthreads();
  }
}

// ---------------- K3: y = LN(xs + relu(ys)@Wg + bg) * g1 + be1  (y: f32) ----------------
__global__ __launch_bounds__(256) void k_res_ln1(const unsigned short* __restrict__ rys,
                                                 const unsigned short* __restrict__ WgT,
                                                 const float* __restrict__ xs,
                                                 const float* __restrict__ bg,
                                                 const float* __restrict__ g1,
                                                 const float* __restrict__ be1,
                                                 float* __restrict__ y) {
  __shared__ float sbuf[16][264];
  int mt = blockIdx.x, tid = threadIdx.x;
  int wave = tid >> 6, lane = tid & 63;
  int r0 = mt * 16;
  f4v acc[4];
#pragma unroll
  for (int i = 0; i < 4; ++i) acc[i] = (f4v){0.f, 0.f, 0.f, 0.f};
#pragma unroll
  for (int kc = 0; kc < 256; kc += 32) {
    bf8v a = load_frag(rys, NDIM, r0, kc);
#pragma unroll
    for (int nt = 0; nt < 4; ++nt) {
      bf8v b = load_frag(WgT, NDIM, wave * 64 + nt * 16, kc);
      acc[nt] = __builtin_amdgcn_mfma_f32_16x16x32_bf16(a, b, acc[nt], 0, 0, 0);
    }
  }
#pragma unroll
  for (int nt = 0; nt < 4; ++nt) {
    int col = wave * 64 + nt * 16 + (lane & 15);
    int rl = ((lane >> 4) << 2);
#pragma unroll
    for (int r = 0; r < 4; ++r)
      sbuf[rl + r][col] = acc[nt][r] + xs[(size_t)(r0 + rl + r) * NDIM + col] + bg[col];
  }
  __syncthreads();
  int rr = tid >> 4, c0 = tid & 15;
  float sum = 0.f, sq = 0.f;
#pragma unroll
  for (int m = 0; m < 16; ++m) {
    float v = sbuf[rr][c0 + 16 * m];
    sum += v; sq += v * v;
  }
#pragma unroll
  for (int o = 1; o < 16; o <<= 1) {
    sum += __shfl_xor(sum, o, 16);
    sq  += __shfl_xor(sq, o, 16);
  }
  float mu = sum * (1.f / 256.f);
  float var = sq * (1.f / 256.f) - mu * mu;
  float rs = rsqrtf(var + 1e-6f);
#pragma unroll
  for (int m = 0; m < 16; ++m) {
    int col = c0 + 16 * m;
    float v = (sbuf[rr][col] - mu) * rs * g1[col] + be1[col];
    y[(size_t)(r0 + rr) * NDIM + col] = v;
  }
}

// ---------------- K4: out = LN(y + relu(y@W1+b1)@W2 + b2) * g2 + be2 ----------------
__global__ __launch_bounds__(256) void k_ffn(const float* __restrict__ y,
                                             const unsigned short* __restrict__ W1T,
                                             const float* __restrict__ b1,
                                             const unsigned short* __restrict__ W2T,
                                             const float* __restrict__ b2,
                                             const float* __restrict__ g2,
                                             const float* __restrict__ be2,
                                             float* __restrict__ out) {
  __shared__ unsigned short hidb[16][1032];
  __shared__ float sbuf[16][264];
  int mt = blockIdx.x, tid = threadIdx.x;
  int wave = tid >> 6, lane = tid & 63;
  int r0 = mt * 16;

  f4v acc1[16];
#pragma unroll
  for (int i = 0; i < 16; ++i) acc1[i] = (f4v){0.f, 0.f, 0.f, 0.f};
#pragma unroll
  for (int kc = 0; kc < 256; kc += 32) {
    bf8v a = load_frag_f32(y, NDIM, r0, kc);
#pragma unroll
    for (int nt = 0; nt < 16; ++nt) {
      bf8v b = load_frag(W1T, NDIM, wave * 256 + nt * 16, kc);
      acc1[nt] = __builtin_amdgcn_mfma_f32_16x16x32_bf16(a, b, acc1[nt], 0, 0, 0);
    }
  }
#pragma unroll
  for (int nt = 0; nt < 16; ++nt) {
    int col = wave * 256 + nt * 16 + (lane & 15);
    int rl = ((lane >> 4) << 2);
#pragma unroll
    for (int r = 0; r < 4; ++r)
      hidb[rl + r][col] = f2bf(fmaxf(acc1[nt][r] + b1[col], 0.f));
  }
  __syncthreads();

  f4v acc2[4];
#pragma unroll
  for (int i = 0; i < 4; ++i) acc2[i] = (f4v){0.f, 0.f, 0.f, 0.f};
  for (int kc = 0; kc < 1024; kc += 32) {
    bf8v a = *(const bf8v*)(&hidb[lane & 15][kc + ((lane >> 4) << 3)]);
#pragma unroll
    for (int nt = 0; nt < 4; ++nt) {
      bf8v b = load_frag(W2T, NFFN, wave * 64 + nt * 16, kc);
      acc2[nt] = __builtin_amdgcn_mfma_f32_16x16x32_bf16(a, b, acc2[nt], 0, 0, 0);
    }
  }
#pragma unroll
  for (int nt = 0; nt < 4; ++nt) {
    int col = wave * 64 + nt * 16 + (lane & 15);
    int rl = ((lane >> 4) << 2);
#pragma unroll
    for (int r = 0; r < 4; ++r)
      sbuf[rl + r][col] = acc2[nt][r] + y[(size_t)(r0 + rl + r) * NDIM + col] + b2[col];
  }
  __syncthreads();
  int rr = tid >> 4, c0 = tid & 15;
  float sum = 0.f, sq = 0.f;
#pragma unroll
  for (int m = 0; m < 16; ++m) {
    float v = sbuf[rr][c0 + 16 * m];
    sum += v; sq += v * v;
  }
#pragma unroll
  for (int o = 1; o < 16; o <<= 1) {
    sum += __shfl_xor(sum, o, 16);
    sq  += __shfl_xor(sq, o, 16);
  }
  float mu = sum * (1.f / 256.f);
  float var = sq * (1.f / 256.f) - mu * mu;
  float rs = rsqrtf(var + 1e-6f);
#pragma unroll
  for (int m = 0; m < 16; ++m) {
    int col = c0 + 16 * m;
    float v = (sbuf[rr][col] - mu) * rs * g2[col] + be2[col];
    out[(size_t)(r0 + rr) * NDIM + col] = v;
  }
}

// ---------------- host ----------------
extern "C" void kernel_launch(void* const* d_in, const int* in_sizes, int n_in,
                              void* d_out, int out_size, void* d_ws, size_t ws_size,
                              hipStream_t stream) {
  const float* xs  = (const float*)d_in[0];
  const float* h0  = (const float*)d_in[1];
  const float* Wi  = (const float*)d_in[2];
  const float* Wh  = (const float*)d_in[3];
  const float* bh  = (const float*)d_in[4];
  const float* Wg  = (const float*)d_in[5];
  const float* bg  = (const float*)d_in[6];
  const float* g1  = (const float*)d_in[7];
  const float* be1 = (const float*)d_in[8];
  const float* W1  = (const float*)d_in[9];
  const float* b1  = (const float*)d_in[10];
  const float* W2  = (const float*)d_in[11];
  const float* b2  = (const float*)d_in[12];
  const float* g2  = (const float*)d_in[13];
  const float* be2 = (const float*)d_in[14];

  char* ws = (char*)d_ws;
  __half* xg = (__half*)(ws + 0);          // f16 [T,768] = 50331648 B
  float*  yb = (float*)(ws + 0);           // reuses xg region AFTER k_gru
  unsigned short* rys = (unsigned short*)(ws + 50331648);   // bf16 [T,256]
  unsigned short* WiT = (unsigned short*)(ws + 67108864);   // 393216 B
  char*           WhQ = (char*)          (ws + 67502080);   // 196608 B
  float*          Fsc = (float*)         (ws + 67698688);   // 3072 B
  unsigned short* WgT = (unsigned short*)(ws + 67895296);
  unsigned short* W1T = (unsigned short*)(ws + 68026368);
  unsigned short* W2T = (unsigned short*)(ws + 68550656);

  k_tr_bf<<<(256 * 768 + 255) / 256, 256, 0, stream>>>(Wi, WiT, 256, 768);
  k_tr_bf<<<(256 * 256 + 255) / 256, 256, 0, stream>>>(Wg, WgT, 256, 256);
  k_tr_bf<<<(256 * 1024 + 255) / 256, 256, 0, stream>>>(W1, W1T, 256, 1024);
  k_tr_bf<<<(1024 * 256 + 255) / 256, 256, 0, stream>>>(W2, W2T, 1024, 256);
  k_prep<<<768, 64, 0, stream>>>(Wh, WhQ, Fsc);

  k_xg<<<dim3(T_LEN / 16, 3), 256, 0, stream>>>(xs, WiT, xg);
  k_gru<<<1, 512, 0, stream>>>(WhQ, Fsc, bh, h0, xg, rys);
  k_res_ln1<<<T_LEN / 16, 256, 0, stream>>>(rys, WgT, xs, bg, g1, be1, yb);
  k_ffn<<<T_LEN / 16, 256, 0, stream>>>(yb, W1T, b1, W2T, b2, g2, be2, (float*)d_out);
}

// Round 7
// 22899.123 us; speedup vs baseline: 1.7459x; 1.3328x over previous
//
#include <hip/hip_runtime.h>
#include <hip/hip_bf16.h>
#include <hip/hip_fp16.h>

#define T_LEN 32768
#define NDIM 256
#define NFFN 1024

typedef __attribute__((ext_vector_type(8))) short bf8v;      // 8 bf16 (4 VGPRs)
typedef __attribute__((ext_vector_type(4))) float f4v;       // f32 MFMA accum
typedef __attribute__((ext_vector_type(4))) int   i4v;       // 4 dwords (16 int8) / i32 accum
typedef _Float16 fp16_t;

__device__ __forceinline__ unsigned short f2bf(float f) {
  union { float f; unsigned int i; } v; v.f = f;
  unsigned int u = v.i;
  u += 0x7FFFu + ((u >> 16) & 1u);   // RNE
  return (unsigned short)(u >> 16);
}

// A/B fragment loaders for mfma_f32_16x16x32_bf16.
__device__ __forceinline__ bf8v load_frag(const unsigned short* base, int ld, int r0, int k0) {
  int lane = threadIdx.x & 63;
  const unsigned short* p = base + (size_t)(r0 + (lane & 15)) * ld + (k0 + ((lane >> 4) << 3));
  return *(const bf8v*)p;
}
__device__ __forceinline__ bf8v load_frag_f32(const float* base, int ld, int r0, int k0) {
  int lane = threadIdx.x & 63;
  const float* p = base + (size_t)(r0 + (lane & 15)) * ld + (k0 + ((lane >> 4) << 3));
  float4 u = *(const float4*)p;
  float4 v = *(const float4*)(p + 4);
  bf8v r;
  r[0] = (short)f2bf(u.x); r[1] = (short)f2bf(u.y); r[2] = (short)f2bf(u.z); r[3] = (short)f2bf(u.w);
  r[4] = (short)f2bf(v.x); r[5] = (short)f2bf(v.y); r[6] = (short)f2bf(v.z); r[7] = (short)f2bf(v.w);
  return r;
}

// ---------------- K0a: transpose f32 [K,N] -> bf16 [N,K] ----------------
__global__ __launch_bounds__(256) void k_tr_bf(const float* __restrict__ src,
                                               unsigned short* __restrict__ dst, int K, int N) {
  int idx = blockIdx.x * 256 + threadIdx.x;
  if (idx >= K * N) return;
  int k = idx / N, n = idx - k * N;
  dst[n * K + k] = f2bf(src[idx]);
}

// ---------------- K0b: quantize Wh f32 [256][768] -> int8 [768][256] + per-col dequant F ---------
__global__ __launch_bounds__(64) void k_prep(const float* __restrict__ Wh,
                                             char* __restrict__ WhQ,
                                             float* __restrict__ F) {
  int j = blockIdx.x, t = threadIdx.x;
  float w[4]; float m = 0.f;
#pragma unroll
  for (int i = 0; i < 4; ++i) {
    w[i] = Wh[(size_t)(t + 64 * i) * 768 + j];
    m = fmaxf(m, fabsf(w[i]));
  }
#pragma unroll
  for (int off = 32; off >= 1; off >>= 1) m = fmaxf(m, __shfl_xor(m, off));
  float mm = fmaxf(m, 1e-20f);
  float inv = 127.f / mm;
#pragma unroll
  for (int i = 0; i < 4; ++i) {
    int qv = (int)rintf(w[i] * inv);
    WhQ[(size_t)j * 256 + t + 64 * i] = (char)qv;
  }
  if (t == 0) F[j] = mm * (1.f / (127.f * 127.f));   // hg = acc_i32 * F
}

// ---------------- K1: xg = xs @ Wi  ([T,256]f32 @ [256,768] -> f16 [T,768]) ----------------
__global__ __launch_bounds__(256) void k_xg(const float* __restrict__ xs,
                                            const unsigned short* __restrict__ WiT,
                                            __half* __restrict__ xg) {
  int mt = blockIdx.x, ns = blockIdx.y;
  int wave = threadIdx.x >> 6, lane = threadIdx.x & 63;
  int r0 = mt * 16;
  f4v acc[4];
#pragma unroll
  for (int i = 0; i < 4; ++i) acc[i] = (f4v){0.f, 0.f, 0.f, 0.f};
#pragma unroll
  for (int kc = 0; kc < 256; kc += 32) {
    bf8v a = load_frag_f32(xs, NDIM, r0, kc);
#pragma unroll
    for (int nt = 0; nt < 4; ++nt) {
      int c0 = ns * 256 + wave * 64 + nt * 16;
      bf8v b = load_frag(WiT, NDIM, c0, kc);
      acc[nt] = __builtin_amdgcn_mfma_f32_16x16x32_bf16(a, b, acc[nt], 0, 0, 0);
    }
  }
#pragma unroll
  for (int nt = 0; nt < 4; ++nt) {
    int col = ns * 256 + wave * 64 + nt * 16 + (lane & 15);
    int rb = r0 + ((lane >> 4) << 2);
#pragma unroll
    for (int r = 0; r < 4; ++r)
      xg[(size_t)(rb + r) * 768 + col] = (__half)acc[nt][r];
  }
}

// ---------------- K2: sequential GRU scan — int8 MFMA recurrence, copy-split gates -------------
// 512 threads (8 waves, 2/SIMD). MFMA part unchanged from R6 (proven): D = A*B,
// A = int8 h broadcast (LDS), B = int8 Wh frags in AGPRs, 24 MFMAs/wave/step.
// NEW: lane computes gates for ONE column jX = (copy&1)?jB:jA (halves gate VALU);
// relu store software-pipelined one step + xg prefetch issued in the MFMA pipe
// shadow (before acc consumption). One barrier/step.
__global__ __launch_bounds__(512, 2) void k_gru(const char* __restrict__ WhQ,
                                                const float* __restrict__ F,
                                                const float* __restrict__ bh,
                                                const float* __restrict__ h0,
                                                const __half* __restrict__ xg,
                                                unsigned short* __restrict__ relu_ys) {
  __shared__ __align__(16) char hbuf[2][256];
  const int tid = threadIdx.x;
  const int w = tid >> 6, lane = tid & 63;
  const int c = lane & 15, copy = lane >> 4;
  const int jA = 32 * w + c, jB = jA + 16;
  const int sel = copy & 1;                  // 0 -> jA, 1 -> jB
  const int jX = sel ? jB : jA;
  const bool writer = (copy < 2);            // copy0 owns jA, copy1 owns jB

  // B-fragments: tiles 0..5 = {r/jA-tile, r/jB-tile, z/jA, z/jB, n/jA, n/jB}
  int cbs[6] = { 32 * w, 32 * w + 16, 256 + 32 * w, 256 + 32 * w + 16,
                 512 + 32 * w, 512 + 32 * w + 16 };
  i4v BQ[6][4];
#pragma unroll
  for (int ti = 0; ti < 6; ++ti) {
    const i4v* p = (const i4v*)(WhQ + (size_t)(cbs[ti] + c) * 256 + copy * 16);
#pragma unroll
    for (int kt = 0; kt < 4; ++kt)
      BQ[ti][kt] = p[kt * 4];              // +kt*64 bytes
  }

  // per-lane (single-column) dequant scales, biases, state
  float Fr = F[jX], Fz = F[256 + jX], Fn = F[512 + jX];
  float bhr = bh[jX], bhz = bh[256 + jX], bhn = bh[512 + jX];
  float h = h0[jX];
  if (writer) {
    int q = max(-127, min(127, (int)rintf(h * 127.f)));
    hbuf[0][jX] = (char)q;
  }
  float xr = (float)xg[jX], xz = (float)xg[256 + jX], xn = (float)xg[512 + jX];
  float prev_relu = 0.f;
  __syncthreads();

  for (int t = 0; t < T_LEN; ++t) {
    const int p = t & 1;
    i4v acc[6];
#pragma unroll
    for (int i = 0; i < 6; ++i) acc[i] = (i4v){0, 0, 0, 0};
#pragma unroll
    for (int kt = 0; kt < 4; ++kt) {
      i4v a = *(const i4v*)(&hbuf[p][kt * 64 + copy * 16]);   // broadcast across c
#pragma unroll
      for (int ti = 0; ti < 6; ++ti)
        acc[ti] = __builtin_amdgcn_mfma_i32_16x16x64_i8(a, BQ[ti][kt], acc[ti], 0, 0, 0);
    }

    // ---- MFMA-shadow zone: independent of acc ----
    if (t > 0 && writer)
      relu_ys[(size_t)(t - 1) * NDIM + jX] = f2bf(prev_relu);
    const __half* row = xg + (size_t)((t + 1) & (T_LEN - 1)) * 768;
    float nxr = (float)row[jX];
    float nxz = (float)row[256 + jX];
    float nxn = (float)row[512 + jX];

    // ---- gate chain for this lane's single column ----
    int ai_r = sel ? acc[1][0] : acc[0][0];
    int ai_z = sel ? acc[3][0] : acc[2][0];
    int ai_n = sel ? acc[5][0] : acc[4][0];
    float hr = (float)ai_r * Fr + bhr;
    float hz = (float)ai_z * Fz + bhz;
    float hn = (float)ai_n * Fn + bhn;
    float r = 1.f / (1.f + __expf(-(xr + hr)));
    float z = 1.f / (1.f + __expf(-(xz + hz)));
    float ar = xn + r * hn;
    float e = __expf(-2.f * fabsf(ar));
    float th = copysignf((1.f - e) / (1.f + e), ar);   // tanh, NaN-safe
    h = (1.f - z) * th + z * h;

    if (writer) {
      int q = max(-127, min(127, (int)rintf(h * 127.f)));
      hbuf[p ^ 1][jX] = (char)q;
    }
    prev_relu = fmaxf(h, 0.f);
    xr = nxr; xz = nxz; xn = nxn;
    __syncthreads();
  }
  if (writer)
    relu_ys[(size_t)(T_LEN - 1) * NDIM + jX] = f2bf(prev_relu);
}

// ---------------- K3: y = LN(xs + relu(ys)@Wg + bg) * g1 + be1  (y: f32) ----------------
__global__ __launch_bounds__(256) void k_res_ln1(const unsigned short* __restrict__ rys,
                                                 const unsigned short* __restrict__ WgT,
                                                 const float* __restrict__ xs,
                                                 const float* __restrict__ bg,
                                                 const float* __restrict__ g1,
                                                 const float* __restrict__ be1,
                                                 float* __restrict__ y) {
  __shared__ float sbuf[16][264];
  int mt = blockIdx.x, tid = threadIdx.x;
  int wave = tid >> 6, lane = tid & 63;
  int r0 = mt * 16;
  f4v acc[4];
#pragma unroll
  for (int i = 0; i < 4; ++i) acc[i] = (f4v){0.f, 0.f, 0.f, 0.f};
#pragma unroll
  for (int kc = 0; kc < 256; kc += 32) {
    bf8v a = load_frag(rys, NDIM, r0, kc);
#pragma unroll
    for (int nt = 0; nt < 4; ++nt) {
      bf8v b = load_frag(WgT, NDIM, wave * 64 + nt * 16, kc);
      acc[nt] = __builtin_amdgcn_mfma_f32_16x16x32_bf16(a, b, acc[nt], 0, 0, 0);
    }
  }
#pragma unroll
  for (int nt = 0; nt < 4; ++nt) {
    int col = wave * 64 + nt * 16 + (lane & 15);
    int rl = ((lane >> 4) << 2);
#pragma unroll
    for (int r = 0; r < 4; ++r)
      sbuf[rl + r][col] = acc[nt][r] + xs[(size_t)(r0 + rl + r) * NDIM + col] + bg[col];
  }
  __syncthreads();
  int rr = tid >> 4, c0 = tid & 15;
  float sum = 0.f, sq = 0.f;
#pragma unroll
  for (int m = 0; m < 16; ++m) {
    float v = sbuf[rr][c0 + 16 * m];
    sum += v; sq += v * v;
  }
#pragma unroll
  for (int o = 1; o < 16; o <<= 1) {
    sum += __shfl_xor(sum, o, 16);
    sq  += __shfl_xor(sq, o, 16);
  }
  float mu = sum * (1.f / 256.f);
  float var = sq * (1.f / 256.f) - mu * mu;
  float rs = rsqrtf(var + 1e-6f);
#pragma unroll
  for (int m = 0; m < 16; ++m) {
    int col = c0 + 16 * m;
    float v = (sbuf[rr][col] - mu) * rs * g1[col] + be1[col];
    y[(size_t)(r0 + rr) * NDIM + col] = v;
  }
}

// ---------------- K4: out = LN(y + relu(y@W1+b1)@W2 + b2) * g2 + be2 ----------------
__global__ __launch_bounds__(256) void k_ffn(const float* __restrict__ y,
                                             const unsigned short* __restrict__ W1T,
                                             const float* __restrict__ b1,
                                             const unsigned short* __restrict__ W2T,
                                             const float* __restrict__ b2,
                                             const float* __restrict__ g2,
                                             const float* __restrict__ be2,
                                             float* __restrict__ out) {
  __shared__ unsigned short hidb[16][1032];
  __shared__ float sbuf[16][264];
  int mt = blockIdx.x, tid = threadIdx.x;
  int wave = tid >> 6, lane = tid & 63;
  int r0 = mt * 16;

  f4v acc1[16];
#pragma unroll
  for (int i = 0; i < 16; ++i) acc1[i] = (f4v){0.f, 0.f, 0.f, 0.f};
#pragma unroll
  for (int kc = 0; kc < 256; kc += 32) {
    bf8v a = load_frag_f32(y, NDIM, r0, kc);
#pragma unroll
    for (int nt = 0; nt < 16; ++nt) {
      bf8v b = load_frag(W1T, NDIM, wave * 256 + nt * 16, kc);
      acc1[nt] = __builtin_amdgcn_mfma_f32_16x16x32_bf16(a, b, acc1[nt], 0, 0, 0);
    }
  }
#pragma unroll
  for (int nt = 0; nt < 16; ++nt) {
    int col = wave * 256 + nt * 16 + (lane & 15);
    int rl = ((lane >> 4) << 2);
#pragma unroll
    for (int r = 0; r < 4; ++r)
      hidb[rl + r][col] = f2bf(fmaxf(acc1[nt][r] + b1[col], 0.f));
  }
  __syncthreads();

  f4v acc2[4];
#pragma unroll
  for (int i = 0; i < 4; ++i) acc2[i] = (f4v){0.f, 0.f, 0.f, 0.f};
  for (int kc = 0; kc < 1024; kc += 32) {
    bf8v a = *(const bf8v*)(&hidb[lane & 15][kc + ((lane >> 4) << 3)]);
#pragma unroll
    for (int nt = 0; nt < 4; ++nt) {
      bf8v b = load_frag(W2T, NFFN, wave * 64 + nt * 16, kc);
      acc2[nt] = __builtin_amdgcn_mfma_f32_16x16x32_bf16(a, b, acc2[nt], 0, 0, 0);
    }
  }
#pragma unroll
  for (int nt = 0; nt < 4; ++nt) {
    int col = wave * 64 + nt * 16 + (lane & 15);
    int rl = ((lane >> 4) << 2);
#pragma unroll
    for (int r = 0; r < 4; ++r)
      sbuf[rl + r][col] = acc2[nt][r] + y[(size_t)(r0 + rl + r) * NDIM + col] + b2[col];
  }
  __syncthreads();
  int rr = tid >> 4, c0 = tid & 15;
  float sum = 0.f, sq = 0.f;
#pragma unroll
  for (int m = 0; m < 16; ++m) {
    float v = sbuf[rr][c0 + 16 * m];
    sum += v; sq += v * v;
  }
#pragma unroll
  for (int o = 1; o < 16; o <<= 1) {
    sum += __shfl_xor(sum, o, 16);
    sq  += __shfl_xor(sq, o, 16);
  }
  float mu = sum * (1.f / 256.f);
  float var = sq * (1.f / 256.f) - mu * mu;
  float rs = rsqrtf(var + 1e-6f);
#pragma unroll
  for (int m = 0; m < 16; ++m) {
    int col = c0 + 16 * m;
    float v = (sbuf[rr][col] - mu) * rs * g2[col] + be2[col];
    out[(size_t)(r0 + rr) * NDIM + col] = v;
  }
}

// ---------------- host ----------------
extern "C" void kernel_launch(void* const* d_in, const int* in_sizes, int n_in,
                              void* d_out, int out_size, void* d_ws, size_t ws_size,
                              hipStream_t stream) {
  const float* xs  = (const float*)d_in[0];
  const float* h0  = (const float*)d_in[1];
  const float* Wi  = (const float*)d_in[2];
  const float* Wh  = (const float*)d_in[3];
  const float* bh  = (const float*)d_in[4];
  const float* Wg  = (const float*)d_in[5];
  const float* bg  = (const float*)d_in[6];
  const float* g1  = (const float*)d_in[7];
  const float* be1 = (const float*)d_in[8];
  const float* W1  = (const float*)d_in[9];
  const float* b1  = (const float*)d_in[10];
  const float* W2  = (const float*)d_in[11];
  const float* b2  = (const float*)d_in[12];
  const float* g2  = (const float*)d_in[13];
  const float* be2 = (const float*)d_in[14];

  char* ws = (char*)d_ws;
  __half* xg = (__half*)(ws + 0);          // f16 [T,768] = 50331648 B
  float*  yb = (float*)(ws + 0);           // reuses xg region AFTER k_gru
  unsigned short* rys = (unsigned short*)(ws + 50331648);   // bf16 [T,256]
  unsigned short* WiT = (unsigned short*)(ws + 67108864);   // 393216 B
  char*           WhQ = (char*)          (ws + 67502080);   // 196608 B
  float*          Fsc = (float*)         (ws + 67698688);   // 3072 B
  unsigned short* WgT = (unsigned short*)(ws + 67895296);
  unsigned short* W1T = (unsigned short*)(ws + 68026368);
  unsigned short* W2T = (unsigned short*)(ws + 68550656);

  k_tr_bf<<<(256 * 768 + 255) / 256, 256, 0, stream>>>(Wi, WiT, 256, 768);
  k_tr_bf<<<(256 * 256 + 255) / 256, 256, 0, stream>>>(Wg, WgT, 256, 256);
  k_tr_bf<<<(256 * 1024 + 255) / 256, 256, 0, stream>>>(W1, W1T, 256, 1024);
  k_tr_bf<<<(1024 * 256 + 255) / 256, 256, 0, stream>>>(W2, W2T, 1024, 256);
  k_prep<<<768, 64, 0, stream>>>(Wh, WhQ, Fsc);

  k_xg<<<dim3(T_LEN / 16, 3), 256, 0, stream>>>(xs, WiT, xg);
  k_gru<<<1, 512, 0, stream>>>(WhQ, Fsc, bh, h0, xg, rys);
  k_res_ln1<<<T_LEN / 16, 256, 0, stream>>>(rys, WgT, xs, bg, g1, be1, yb);
  k_ffn<<<T_LEN / 16, 256, 0, stream>>>(yb, W1T, b1, W2T, b2, g2, be2, (float*)d_out);
}

// Round 8
// 20919.345 us; speedup vs baseline: 1.9111x; 1.0946x over previous
//
#include <hip/hip_runtime.h>
#include <hip/hip_bf16.h>
#include <hip/hip_fp16.h>

#define T_LEN 32768
#define NDIM 256
#define NFFN 1024

typedef __attribute__((ext_vector_type(8))) short bf8v;      // 8 bf16 (4 VGPRs)
typedef __attribute__((ext_vector_type(8))) _Float16 h8v;    // 8 f16 (4 VGPRs)
typedef __attribute__((ext_vector_type(4))) float f4v;       // f32 MFMA accum
typedef __attribute__((ext_vector_type(4))) int   i4v;       // 4 dwords (16 int8) / i32 accum
typedef _Float16 fp16_t;

__device__ __forceinline__ unsigned short f2bf(float f) {
  union { float f; unsigned int i; } v; v.f = f;
  unsigned int u = v.i;
  u += 0x7FFFu + ((u >> 16) & 1u);   // RNE
  return (unsigned short)(u >> 16);
}
__device__ __forceinline__ h8v as_h8(bf8v x) {
  union { bf8v b; h8v h; } u; u.b = x; return u.h;
}

// A/B fragment loaders for 16x16x32 MFMA (bf16 or f16 — same byte layout).
__device__ __forceinline__ bf8v load_frag(const unsigned short* base, int ld, int r0, int k0) {
  int lane = threadIdx.x & 63;
  const unsigned short* p = base + (size_t)(r0 + (lane & 15)) * ld + (k0 + ((lane >> 4) << 3));
  return *(const bf8v*)p;
}
__device__ __forceinline__ bf8v load_frag_f32(const float* base, int ld, int r0, int k0) {
  int lane = threadIdx.x & 63;
  const float* p = base + (size_t)(r0 + (lane & 15)) * ld + (k0 + ((lane >> 4) << 3));
  float4 u = *(const float4*)p;
  float4 v = *(const float4*)(p + 4);
  bf8v r;
  r[0] = (short)f2bf(u.x); r[1] = (short)f2bf(u.y); r[2] = (short)f2bf(u.z); r[3] = (short)f2bf(u.w);
  r[4] = (short)f2bf(v.x); r[5] = (short)f2bf(v.y); r[6] = (short)f2bf(v.z); r[7] = (short)f2bf(v.w);
  return r;
}

// ---------------- K0a: transpose f32 [K,N] -> bf16 [N,K] ----------------
__global__ __launch_bounds__(256) void k_tr_bf(const float* __restrict__ src,
                                               unsigned short* __restrict__ dst, int K, int N) {
  int idx = blockIdx.x * 256 + threadIdx.x;
  if (idx >= K * N) return;
  int k = idx / N, n = idx - k * N;
  dst[n * K + k] = f2bf(src[idx]);
}
// ---------------- K0a': transpose f32 [K,N] -> f16 [N,K] ----------------
__global__ __launch_bounds__(256) void k_tr_h(const float* __restrict__ src,
                                              fp16_t* __restrict__ dst, int K, int N) {
  int idx = blockIdx.x * 256 + threadIdx.x;
  if (idx >= K * N) return;
  int k = idx / N, n = idx - k * N;
  dst[n * K + k] = (fp16_t)src[idx];
}

// ---------------- K0b: quantize Wh f32 [256][768] -> int8 [768][256] + per-col dequant F ---------
__global__ __launch_bounds__(64) void k_prep(const float* __restrict__ Wh,
                                             char* __restrict__ WhQ,
                                             float* __restrict__ F) {
  int j = blockIdx.x, t = threadIdx.x;
  float w[4]; float m = 0.f;
#pragma unroll
  for (int i = 0; i < 4; ++i) {
    w[i] = Wh[(size_t)(t + 64 * i) * 768 + j];
    m = fmaxf(m, fabsf(w[i]));
  }
#pragma unroll
  for (int off = 32; off >= 1; off >>= 1) m = fmaxf(m, __shfl_xor(m, off));
  float mm = fmaxf(m, 1e-20f);
  float inv = 127.f / mm;
#pragma unroll
  for (int i = 0; i < 4; ++i) {
    int qv = (int)rintf(w[i] * inv);
    WhQ[(size_t)j * 256 + t + 64 * i] = (char)qv;
  }
  if (t == 0) F[j] = mm * (1.f / (127.f * 127.f));   // hg = acc_i32 * F
}

// ---------------- K1: xgT = (xs @ Wi)^T  ([T,256]f32 @ [256,768] -> f16 [768][T]) ----------------
__global__ __launch_bounds__(256) void k_xg(const float* __restrict__ xs,
                                            const unsigned short* __restrict__ WiT,
                                            fp16_t* __restrict__ xgT) {
  int mt = blockIdx.x, ns = blockIdx.y;
  int wave = threadIdx.x >> 6, lane = threadIdx.x & 63;
  int r0 = mt * 16;
  f4v acc[4];
#pragma unroll
  for (int i = 0; i < 4; ++i) acc[i] = (f4v){0.f, 0.f, 0.f, 0.f};
#pragma unroll
  for (int kc = 0; kc < 256; kc += 32) {
    bf8v a = load_frag_f32(xs, NDIM, r0, kc);
#pragma unroll
    for (int nt = 0; nt < 4; ++nt) {
      int c0 = ns * 256 + wave * 64 + nt * 16;
      bf8v b = load_frag(WiT, NDIM, c0, kc);
      acc[nt] = __builtin_amdgcn_mfma_f32_16x16x32_bf16(a, b, acc[nt], 0, 0, 0);
    }
  }
  // transposed store: xgT[col][rb..rb+3] as one 8B chunk
#pragma unroll
  for (int nt = 0; nt < 4; ++nt) {
    int col = ns * 256 + wave * 64 + nt * 16 + (lane & 15);
    int rb = r0 + ((lane >> 4) << 2);
    union { int2 v; fp16_t h[4]; } pk;
    pk.h[0] = (fp16_t)acc[nt][0]; pk.h[1] = (fp16_t)acc[nt][1];
    pk.h[2] = (fp16_t)acc[nt][2]; pk.h[3] = (fp16_t)acc[nt][3];
    *(int2*)(xgT + (size_t)col * T_LEN + rb) = pk.v;
  }
}

// ---------------- K2: sequential GRU scan — int8 MFMA recurrence, 8-step unroll ----------------
// 512 threads (8 waves, 2/SIMD). MFMA: A = int8 h broadcast (LDS), B = int8 Wh
// frags in AGPRs, 24 MFMAs/wave/step, persistent-zero C for the first K-chunk.
// Gate inputs from xgT[768][T]: one dwordx4 per gate per 8 steps, double-buffered
// one block ahead; x8 unroll makes element extraction static. rys stored f16.
__global__ __launch_bounds__(512, 2) void k_gru(const char* __restrict__ WhQ,
                                                const float* __restrict__ F,
                                                const float* __restrict__ bh,
                                                const float* __restrict__ h0,
                                                const fp16_t* __restrict__ xgT,
                                                fp16_t* __restrict__ relu_ys) {
  __shared__ __align__(16) char hbuf[2][256];
  const int tid = threadIdx.x;
  const int w = tid >> 6, lane = tid & 63;
  const int c = lane & 15, copy = lane >> 4;
  const int jA = 32 * w + c, jB = jA + 16;
  const int sel = copy & 1;                  // 0 -> jA, 1 -> jB
  const int jX = sel ? jB : jA;
  const bool writer = (copy < 2);            // copy0 owns jA, copy1 owns jB

  // B-fragments: tiles 0..5 = {r/jA-tile, r/jB-tile, z/jA, z/jB, n/jA, n/jB}
  int cbs[6] = { 32 * w, 32 * w + 16, 256 + 32 * w, 256 + 32 * w + 16,
                 512 + 32 * w, 512 + 32 * w + 16 };
  i4v BQ[6][4];
#pragma unroll
  for (int ti = 0; ti < 6; ++ti) {
    const i4v* p = (const i4v*)(WhQ + (size_t)(cbs[ti] + c) * 256 + copy * 16);
#pragma unroll
    for (int kt = 0; kt < 4; ++kt)
      BQ[ti][kt] = p[kt * 4];              // +kt*64 bytes
  }
  const i4v IZERO = (i4v){0, 0, 0, 0};     // persistent zero C operand

  // per-lane (single-column) dequant scales, biases, state
  float Fr = F[jX], Fz = F[256 + jX], Fn = F[512 + jX];
  float bhr = bh[jX], bhz = bh[256 + jX], bhn = bh[512 + jX];
  float h = h0[jX];
  if (writer) {
    int q = max(-127, min(127, (int)rintf(h * 127.f)));
    hbuf[0][jX] = (char)q;
  }
  // xg stream pointers (transposed layout: contiguous in t)
  const fp16_t* xrp = xgT + (size_t)jX * T_LEN;
  const fp16_t* xzp = xgT + (size_t)(256 + jX) * T_LEN;
  const fp16_t* xnp = xgT + (size_t)(512 + jX) * T_LEN;
  union U8h { int4 v; fp16_t e[8]; };
  U8h cr, cz, cn;
  cr.v = *(const int4*)(xrp);
  cz.v = *(const int4*)(xzp);
  cn.v = *(const int4*)(xnp);
  float prev_relu = 0.f;
  __syncthreads();

  for (int tb = 0; tb < T_LEN; tb += 8) {
    // prefetch next 8-step block (wraps at end; values unused then)
    const int tn = (tb + 8) & (T_LEN - 1);
    U8h nr, nz, nn2;
    nr.v  = *(const int4*)(xrp + tn);
    nz.v  = *(const int4*)(xzp + tn);
    nn2.v = *(const int4*)(xnp + tn);
#pragma unroll
    for (int tt = 0; tt < 8; ++tt) {
      const int t = tb + tt;
      const int p = tt & 1;                // tb multiple of 8 -> parity consistent
      i4v acc[6];
      {
        i4v a0 = *(const i4v*)(&hbuf[p][copy * 16]);
#pragma unroll
        for (int ti = 0; ti < 6; ++ti)
          acc[ti] = __builtin_amdgcn_mfma_i32_16x16x64_i8(a0, BQ[ti][0], IZERO, 0, 0, 0);
      }
#pragma unroll
      for (int kt = 1; kt < 4; ++kt) {
        i4v a = *(const i4v*)(&hbuf[p][kt * 64 + copy * 16]);
#pragma unroll
        for (int ti = 0; ti < 6; ++ti)
          acc[ti] = __builtin_amdgcn_mfma_i32_16x16x64_i8(a, BQ[ti][kt], acc[ti], 0, 0, 0);
      }

      // ---- MFMA-shadow zone: independent of acc ----
      if ((tt > 0 || tb > 0) && writer)
        relu_ys[(size_t)(t - 1) * NDIM + jX] = (fp16_t)prev_relu;
      float xr = (float)cr.e[tt];
      float xz = (float)cz.e[tt];
      float xn = (float)cn.e[tt];

      // ---- gate chain for this lane's single column ----
      int ai_r = sel ? acc[1][0] : acc[0][0];
      int ai_z = sel ? acc[3][0] : acc[2][0];
      int ai_n = sel ? acc[5][0] : acc[4][0];
      float hr = (float)ai_r * Fr + bhr;
      float hz = (float)ai_z * Fz + bhz;
      float hn = (float)ai_n * Fn + bhn;
      float r = 1.f / (1.f + __expf(-(xr + hr)));
      float z = 1.f / (1.f + __expf(-(xz + hz)));
      float ar = xn + r * hn;
      float e = __expf(-2.f * fabsf(ar));
      float th = copysignf((1.f - e) / (1.f + e), ar);   // tanh, NaN-safe
      h = (1.f - z) * th + z * h;

      if (writer) {
        int q = max(-127, min(127, (int)rintf(h * 127.f)));
        hbuf[p ^ 1][jX] = (char)q;
      }
      prev_relu = fmaxf(h, 0.f);
      __syncthreads();
    }
    cr = nr; cz = nz; cn = nn2;
  }
  if (writer)
    relu_ys[(size_t)(T_LEN - 1) * NDIM + jX] = (fp16_t)prev_relu;
}

// ---------------- K3: y = LN(xs + relu(ys)@Wg + bg) * g1 + be1  (y: f32; rys,Wg: f16) ----------
__global__ __launch_bounds__(256) void k_res_ln1(const unsigned short* __restrict__ rys,
                                                 const unsigned short* __restrict__ WgT,
                                                 const float* __restrict__ xs,
                                                 const float* __restrict__ bg,
                                                 const float* __restrict__ g1,
                                                 const float* __restrict__ be1,
                                                 float* __restrict__ y) {
  __shared__ float sbuf[16][264];
  int mt = blockIdx.x, tid = threadIdx.x;
  int wave = tid >> 6, lane = tid & 63;
  int r0 = mt * 16;
  f4v acc[4];
#pragma unroll
  for (int i = 0; i < 4; ++i) acc[i] = (f4v){0.f, 0.f, 0.f, 0.f};
#pragma unroll
  for (int kc = 0; kc < 256; kc += 32) {
    h8v a = as_h8(load_frag(rys, NDIM, r0, kc));
#pragma unroll
    for (int nt = 0; nt < 4; ++nt) {
      h8v b = as_h8(load_frag(WgT, NDIM, wave * 64 + nt * 16, kc));
      acc[nt] = __builtin_amdgcn_mfma_f32_16x16x32_f16(a, b, acc[nt], 0, 0, 0);
    }
  }
#pragma unroll
  for (int nt = 0; nt < 4; ++nt) {
    int col = wave * 64 + nt * 16 + (lane & 15);
    int rl = ((lane >> 4) << 2);
#pragma unroll
    for (int r = 0; r < 4; ++r)
      sbuf[rl + r][col] = acc[nt][r] + xs[(size_t)(r0 + rl + r) * NDIM + col] + bg[col];
  }
  __syncthreads();
  int rr = tid >> 4, c0 = tid & 15;
  float sum = 0.f, sq = 0.f;
#pragma unroll
  for (int m = 0; m < 16; ++m) {
    float v = sbuf[rr][c0 + 16 * m];
    sum += v; sq += v * v;
  }
#pragma unroll
  for (int o = 1; o < 16; o <<= 1) {
    sum += __shfl_xor(sum, o, 16);
    sq  += __shfl_xor(sq, o, 16);
  }
  float mu = sum * (1.f / 256.f);
  float var = sq * (1.f / 256.f) - mu * mu;
  float rs = rsqrtf(var + 1e-6f);
#pragma unroll
  for (int m = 0; m < 16; ++m) {
    int col = c0 + 16 * m;
    float v = (sbuf[rr][col] - mu) * rs * g1[col] + be1[col];
    y[(size_t)(r0 + rr) * NDIM + col] = v;
  }
}

// ---------------- K4: out = LN(y + relu(y@W1+b1)@W2 + b2) * g2 + be2 ----------------
__global__ __launch_bounds__(256) void k_ffn(const float* __restrict__ y,
                                             const unsigned short* __restrict__ W1T,
                                             const float* __restrict__ b1,
                                             const unsigned short* __restrict__ W2T,
                                             const float* __restrict__ b2,
                                             const float* __restrict__ g2,
                                             const float* __restrict__ be2,
                                             float* __restrict__ out) {
  __shared__ unsigned short hidb[16][1032];
  __shared__ float sbuf[16][264];
  int mt = blockIdx.x, tid = threadIdx.x;
  int wave = tid >> 6, lane = tid & 63;
  int r0 = mt * 16;

  f4v acc1[16];
#pragma unroll
  for (int i = 0; i < 16; ++i) acc1[i] = (f4v){0.f, 0.f, 0.f, 0.f};
#pragma unroll
  for (int kc = 0; kc < 256; kc += 32) {
    bf8v a = load_frag_f32(y, NDIM, r0, kc);
#pragma unroll
    for (int nt = 0; nt < 16; ++nt) {
      bf8v b = load_frag(W1T, NDIM, wave * 256 + nt * 16, kc);
      acc1[nt] = __builtin_amdgcn_mfma_f32_16x16x32_bf16(a, b, acc1[nt], 0, 0, 0);
    }
  }
#pragma unroll
  for (int nt = 0; nt < 16; ++nt) {
    int col = wave * 256 + nt * 16 + (lane & 15);
    int rl = ((lane >> 4) << 2);
#pragma unroll
    for (int r = 0; r < 4; ++r)
      hidb[rl + r][col] = f2bf(fmaxf(acc1[nt][r] + b1[col], 0.f));
  }
  __syncthreads();

  f4v acc2[4];
#pragma unroll
  for (int i = 0; i < 4; ++i) acc2[i] = (f4v){0.f, 0.f, 0.f, 0.f};
  for (int kc = 0; kc < 1024; kc += 32) {
    bf8v a = *(const bf8v*)(&hidb[lane & 15][kc + ((lane >> 4) << 3)]);
#pragma unroll
    for (int nt = 0; nt < 4; ++nt) {
      bf8v b = load_frag(W2T, NFFN, wave * 64 + nt * 16, kc);
      acc2[nt] = __builtin_amdgcn_mfma_f32_16x16x32_bf16(a, b, acc2[nt], 0, 0, 0);
    }
  }
#pragma unroll
  for (int nt = 0; nt < 4; ++nt) {
    int col = wave * 64 + nt * 16 + (lane & 15);
    int rl = ((lane >> 4) << 2);
#pragma unroll
    for (int r = 0; r < 4; ++r)
      sbuf[rl + r][col] = acc2[nt][r] + y[(size_t)(r0 + rl + r) * NDIM + col] + b2[col];
  }
  __syncthreads();
  int rr = tid >> 4, c0 = tid & 15;
  float sum = 0.f, sq = 0.f;
#pragma unroll
  for (int m = 0; m < 16; ++m) {
    float v = sbuf[rr][c0 + 16 * m];
    sum += v; sq += v * v;
  }
#pragma unroll
  for (int o = 1; o < 16; o <<= 1) {
    sum += __shfl_xor(sum, o, 16);
    sq  += __shfl_xor(sq, o, 16);
  }
  float mu = sum * (1.f / 256.f);
  float var = sq * (1.f / 256.f) - mu * mu;
  float rs = rsqrtf(var + 1e-6f);
#pragma unroll
  for (int m = 0; m < 16; ++m) {
    int col = c0 + 16 * m;
    float v = (sbuf[rr][col] - mu) * rs * g2[col] + be2[col];
    out[(size_t)(r0 + rr) * NDIM + col] = v;
  }
}

// ---------------- host ----------------
extern "C" void kernel_launch(void* const* d_in, const int* in_sizes, int n_in,
                              void* d_out, int out_size, void* d_ws, size_t ws_size,
                              hipStream_t stream) {
  const float* xs  = (const float*)d_in[0];
  const float* h0  = (const float*)d_in[1];
  const float* Wi  = (const float*)d_in[2];
  const float* Wh  = (const float*)d_in[3];
  const float* bh  = (const float*)d_in[4];
  const float* Wg  = (const float*)d_in[5];
  const float* bg  = (const float*)d_in[6];
  const float* g1  = (const float*)d_in[7];
  const float* be1 = (const float*)d_in[8];
  const float* W1  = (const float*)d_in[9];
  const float* b1  = (const float*)d_in[10];
  const float* W2  = (const float*)d_in[11];
  const float* b2  = (const float*)d_in[12];
  const float* g2  = (const float*)d_in[13];
  const float* be2 = (const float*)d_in[14];

  char* ws = (char*)d_ws;
  fp16_t* xgT = (fp16_t*)(ws + 0);         // f16 [768][T] = 50331648 B
  float*  yb  = (float*)(ws + 0);          // reuses xgT region AFTER k_gru
  fp16_t* rys = (fp16_t*)(ws + 50331648);  // f16 [T,256] = 16777216 B
  unsigned short* WiT = (unsigned short*)(ws + 67108864);   // 393216 B
  char*           WhQ = (char*)          (ws + 67502080);   // 196608 B
  float*          Fsc = (float*)         (ws + 67698688);   // 3072 B
  fp16_t*         WgT = (fp16_t*)        (ws + 67895296);   // 131072 B (f16 now)
  unsigned short* W1T = (unsigned short*)(ws + 68026368);
  unsigned short* W2T = (unsigned short*)(ws + 68550656);

  k_tr_bf<<<(256 * 768 + 255) / 256, 256, 0, stream>>>(Wi, WiT, 256, 768);
  k_tr_h <<<(256 * 256 + 255) / 256, 256, 0, stream>>>(Wg, WgT, 256, 256);
  k_tr_bf<<<(256 * 1024 + 255) / 256, 256, 0, stream>>>(W1, W1T, 256, 1024);
  k_tr_bf<<<(1024 * 256 + 255) / 256, 256, 0, stream>>>(W2, W2T, 1024, 256);
  k_prep<<<768, 64, 0, stream>>>(Wh, WhQ, Fsc);

  k_xg<<<dim3(T_LEN / 16, 3), 256, 0, stream>>>(xs, WiT, xgT);
  k_gru<<<1, 512, 0, stream>>>(WhQ, Fsc, bh, h0, xgT, rys);
  k_res_ln1<<<T_LEN / 16, 256, 0, stream>>>((const unsigned short*)rys, (const unsigned short*)WgT,
                                            xs, bg, g1, be1, yb);
  k_ffn<<<T_LEN / 16, 256, 0, stream>>>(yb, W1T, b1, W2T, b2, g2, be2, (float*)d_out);
}